// Round 22
// baseline (80.235 us; speedup 1.0000x reference)
//
#include <hip/hip_runtime.h>

typedef __bf16 bf16;
typedef __attribute__((ext_vector_type(4))) __bf16 bf16x4;
typedef __attribute__((ext_vector_type(8))) __bf16 bf16x8;
typedef __attribute__((ext_vector_type(4))) float f32x4;
typedef unsigned int u32;

#define MFMA16(a, b, c) __builtin_amdgcn_mfma_f32_16x16x32_bf16((a), (b), (c), 0, 0, 0)
#define LOG2E 1.4426950408889634f
#define AS1 __attribute__((address_space(1)))
#define AS3 __attribute__((address_space(3)))
#define GLL16(g, l) __builtin_amdgcn_global_load_lds((const AS1 u32*)(g), (AS3 u32*)(l), 16, 0, 0)

// KV chunk, per (b, kt=0..7): 81920 bytes =
//  [0,16384):     K tile [128 q][64 o] bf16, identity rows, 16B-blk swz ^(q&7)
//  [16384,81920): V packed for DIRECT wave-fragment loads: octet (c, mm)
//     (mm = kv>>3 within chunk) at byte 16384 + (c>>6)<<14 + (mm>>2)<<12 +
//     ((c>>4)&3)<<10 + (mm&3)<<8 + (c&15)<<4.  attn wave w: load k=4kb+ct at
//     (w<<14)+(k<<10)+(lane<<4) == A-frag (c=64w+16ct+l16, octet mm=4kb+u).

// ---------------------------------------------------------------------------
// Kernel 1: W hi/lo split only (tiny, 32 blocks).
// ---------------------------------------------------------------------------
__global__ __launch_bounds__(256) void wprep_kernel(const float* __restrict__ Wq,
                                                    const float* __restrict__ Wk,
                                                    const int* __restrict__ flag,
                                                    bf16* __restrict__ Wbh,
                                                    bf16* __restrict__ Wbl) {
  const int bx = blockIdx.x, t = threadIdx.x;
  int z = bx >> 4;
  const float* src = (z == 0) ? Wq : ((flag[0] != 0) ? Wq : Wk);
  const float sc = (z == 0) ? LOG2E : 1.0f;  // exp2-domain softmax
  int i = ((((bx & 15) << 8) + t) << 2);
  float4 vv = *(const float4*)(src + i);
  vv.x *= sc; vv.y *= sc; vv.z *= sc; vv.w *= sc;
  bf16x4 hi, lo;
  hi[0] = (bf16)vv.x; lo[0] = (bf16)(vv.x - (float)hi[0]);
  hi[1] = (bf16)vv.y; lo[1] = (bf16)(vv.y - (float)hi[1]);
  hi[2] = (bf16)vv.z; lo[2] = (bf16)(vv.z - (float)hi[2]);
  hi[3] = (bf16)vv.w; lo[3] = (bf16)(vv.w - (float)hi[3]);
  *(bf16x4*)(Wbh + (z << 14) + i) = hi;
  *(bf16x4*)(Wbl + (z << 14) + i) = lo;
}

// ---------------------------------------------------------------------------
// Kernel 2: MERGED proj + V-pack. Proj re-tiled to 32-px blocks (4x more
// blocks, 4x shorter serial chain -> latency hidden by residency).
// blocks [0,2048): projection. x=bid&31 (32-px tile), b=(bid>>5)&31, z=bid>>10.
//   Wave w: (wo=w>>1) 32-o half, (wp=w&1) 16-px half. 32 MFMA/wave.
//   z=0 -> Qp (log2e-scaled); z=1 -> KV K-part (identity rows + blk swz).
// blocks [2048,6144): kf fp32 -> KV V-region bf16 packed (R12 verbatim).
// ---------------------------------------------------------------------------
__global__ __launch_bounds__(256) void prep_kernel(const float* __restrict__ qf,
                                                   const float* __restrict__ kf,
                                                   const bf16* __restrict__ Wbh,
                                                   const bf16* __restrict__ Wbl,
                                                   const float* __restrict__ bq,
                                                   const float* __restrict__ bk,
                                                   const int* __restrict__ flag,
                                                   bf16* __restrict__ Qp,
                                                   bf16* __restrict__ KV) {
  const int bid = blockIdx.x, t = threadIdx.x;
  if (bid >= 2048) {
    // ---- V-pack: (b, c, q8) -> KV V-region, bf16, fragment-packed ----
    int i = ((bid - 2048) << 8) + t;
    int q8 = i & 127, c = (i >> 7) & 255, b = i >> 15;
    const float* src = kf + ((size_t)(((b << 8) + c)) << 10) + (q8 << 3);
    float4 f0 = *(const float4*)src;
    float4 f1 = *(const float4*)(src + 4);
    bf16x8 v;
    v[0] = (bf16)f0.x; v[1] = (bf16)f0.y; v[2] = (bf16)f0.z; v[3] = (bf16)f0.w;
    v[4] = (bf16)f1.x; v[5] = (bf16)f1.y; v[6] = (bf16)f1.z; v[7] = (bf16)f1.w;
    int kt = q8 >> 4, mm = q8 & 15;
    char* dst = (char*)KV + (size_t)((b << 3) + kt) * 81920 + 16384 +
                ((c >> 6) << 14) + ((mm >> 2) << 12) + (((c >> 4) & 3) << 10) +
                ((mm & 3) << 8) + ((c & 15) << 4);
    *(bf16x8*)dst = v;
    return;
  }
  // ---- projection (32-px tiles) ----
  const int x = bid & 31, b = (bid >> 5) & 31, z = bid >> 10;
  const float* xg = z ? kf : qf;
  const bf16* Wh = Wbh + z * 16384;
  const bf16* Wl = Wbl + z * 16384;
  const float* bias = z ? (flag[0] ? bq : bk) : bq;

  const int w = t >> 6, lane = t & 63;
  const int g = lane >> 4, l16 = lane & 15;
  const int wo = w >> 1, wp = w & 1;
  const int o0 = wo << 5;                     // 32-o half
  const int pbase = (x << 5) + (wp << 4);     // 16-px half

  f32x4 acc[2];  // [ot]: o = o0 + 16ot + 4g + r, px col = l16
#pragma unroll
  for (int ot = 0; ot < 2; ++ot) {
    float4 bv = *(const float4*)(bias + o0 + (ot << 4) + (g << 2));
    if (z == 0) { bv.x *= LOG2E; bv.y *= LOG2E; bv.z *= LOG2E; bv.w *= LOG2E; }
    acc[ot] = (f32x4){bv.x, bv.y, bv.z, bv.w};
  }

  const float* xb = xg + ((((b << 8) + (g << 3)) << 10) + pbase + l16);
  const bf16* whb = Wh + ((o0 + l16) << 8) + (g << 3);
  const bf16* wlb = Wl + ((o0 + l16) << 8) + (g << 3);

  for (int kk = 0; kk < 8; ++kk) {
    bf16x8 ah[2], al[2];
#pragma unroll
    for (int ot = 0; ot < 2; ++ot) {
      ah[ot] = *(const bf16x8*)(whb + (ot << 12) + (kk << 5));
      al[ot] = *(const bf16x8*)(wlb + (ot << 12) + (kk << 5));
    }
    const float* xk = xb + (kk << 15);
    float xv[8];
#pragma unroll
    for (int j = 0; j < 8; ++j) xv[j] = xk[j << 10];
    bf16x8 xf;
#pragma unroll
    for (int j = 0; j < 8; ++j) xf[j] = (bf16)xv[j];
#pragma unroll
    for (int ot = 0; ot < 2; ++ot) {
      acc[ot] = MFMA16(ah[ot], xf, acc[ot]);
      acc[ot] = MFMA16(al[ot], xf, acc[ot]);
    }
  }

#pragma unroll
  for (int ot = 0; ot < 2; ++ot) {
    bf16x4 q4;
#pragma unroll
    for (int r = 0; r < 4; ++r) q4[r] = (bf16)acc[ot][r];
    int p = pbase + l16;
    if (z == 0) {
      *(bf16x4*)(Qp + ((((b << 10) + p)) << 6) + o0 + (ot << 4) + (g << 2)) = q4;
    } else {
      int kt = p >> 7, q = p & 127;
      int blk = (o0 >> 3) + (ot << 1) + (g >> 1);
      char* dst = (char*)KV + (size_t)((b << 3) + kt) * 81920 + q * 128 +
                  16 * (blk ^ (q & 7)) + ((g & 1) << 3);
      *(bf16x4*)dst = q4;
    }
  }
}

// ---------------------------------------------------------------------------
// Kernel 3: fused flash attention (R12 verbatim). grid 512 (XCD-swz) x 256.
// KVBLK=128, 8 iters, no-max exp2 softmax, V global->VGPR packed frags,
// P via sP (in-lane octets), K gll dbuf, 2 barriers/iter.
// ---------------------------------------------------------------------------
__global__ __launch_bounds__(256, 2) void attn_kernel(const bf16* __restrict__ KV,
                                                      const bf16* __restrict__ Qp,
                                                      float* __restrict__ out) {
  const int bid = blockIdx.x;
  const int wkid = ((bid & 7) << 6) + (bid >> 3);  // bijective: 512 % 8 == 0
  const int b = wkid >> 4, ptile = wkid & 15;
  const int p0 = ptile << 6;
  const int t = threadIdx.x;
  const int w = t >> 6, lane = t & 63;
  const int u = lane >> 4, l16 = lane & 15;

  __shared__ __align__(16) unsigned char sK[2][16384];  // K dbuf (gll target)
  __shared__ __align__(16) unsigned char sP[16384];     // [64 px][128 kv], swz
  __shared__ float sL[64];

  // Q B-fragments for this wave's 16 px (col=px, k=o)
  const bf16* qb = Qp + (((size_t)((b << 10) + p0 + (w << 4) + l16)) << 6) + (u << 3);
  const bf16x8 qa0 = *(const bf16x8*)qb;
  const bf16x8 qa1 = *(const bf16x8*)(qb + 32);

  const char* chunk0 = (const char*)KV + (size_t)b * (8 * 81920);
  const int Rb = ((l16 >> 2) << 3) + ((l16 & 3) << 1);  // K row perm base

  f32x4 acc[4][4];  // [pg][ct]: c = 64w + 16ct + 4u + r ; px = 16pg + l16
#pragma unroll
  for (int i = 0; i < 4; ++i)
#pragma unroll
    for (int j = 0; j < 4; ++j) acc[i][j] = (f32x4){0.f, 0.f, 0.f, 0.f};
  float l_ = 0.f;

  const int prow = (w << 4) + l16, pswz = prow & 7;

  // ---- prologue: stage K_0 (4 gll/wave) ----
  {
    const char* g = chunk0 + (w << 12) + (lane << 4);
    unsigned char* l = sK[0] + (w << 12);
#pragma unroll
    for (int op = 0; op < 4; ++op) GLL16(g + op * 1024, l + op * 1024);
  }
  asm volatile("s_waitcnt vmcnt(0)" ::: "memory");
  __syncthreads();

  int cur = 0;
  for (int kt = 0; kt < 8; ++kt) {
    // ---- V_t -> regs: 16 coalesced 1KB loads (packed A-fragments) ----
    bf16x8 vr[16];  // vr[4kb+ct] = V A-frag (c=64w+16ct+l16, octet 4kb+u)
    const char* vsrc = chunk0 + kt * 81920 + 16384 + (w << 14) + (lane << 4);
#pragma unroll
    for (int k = 0; k < 16; ++k) vr[k] = *(const bf16x8*)(vsrc + (k << 10));
    // ---- K_{t+1} gll into other buffer ----
    if (kt < 7) {
      const char* g = chunk0 + (kt + 1) * 81920 + (w << 12) + (lane << 4);
      unsigned char* l = sK[cur ^ 1] + (w << 12);
#pragma unroll
      for (int op = 0; op < 4; ++op) GLL16(g + op * 1024, l + op * 1024);
    }
    const unsigned char* sKc = sK[cur];

    // ---- S^T = K·Q^T (16 mfma, permuted K rows from swizzled LDS) ----
    f32x4 s[8];
#pragma unroll
    for (int qt = 0; qt < 8; ++qt) {
      const int R = Rb + (qt & 1) + ((qt >> 1) << 5);
      const int rb = R * 128;
      bf16x8 k0 = *(const bf16x8*)(sKc + rb + 16 * (u ^ (R & 7)));
      bf16x8 k1 = *(const bf16x8*)(sKc + rb + 16 * ((u + 4) ^ (R & 7)));
      f32x4 z = (f32x4){0.f, 0.f, 0.f, 0.f};
      z = MFMA16(k0, qa0, z);
      s[qt] = MFMA16(k1, qa1, z);
    }
    // ---- NO-MAX softmax: P = exp2(S); l += sum ----
#pragma unroll
    for (int qt = 0; qt < 8; ++qt)
#pragma unroll
      for (int r = 0; r < 4; ++r) s[qt][r] = exp2f(s[qt][r]);
    float rs = 0.f;
#pragma unroll
    for (int qt = 0; qt < 8; ++qt)
      rs += (s[qt][0] + s[qt][1]) + (s[qt][2] + s[qt][3]);
    rs += __shfl_xor(rs, 16);
    rs += __shfl_xor(rs, 32);
    l_ += rs;
    // ---- P -> bf16 octets (in-lane), publish 4 b128 ----
#pragma unroll
    for (int a = 0; a < 4; ++a) {
      bf16x8 pb;
#pragma unroll
      for (int r = 0; r < 4; ++r) {
        pb[2 * r] = (bf16)s[2 * a][r];
        pb[2 * r + 1] = (bf16)s[2 * a + 1][r];
      }
      *(bf16x8*)(sP + prow * 256 + 16 * (((a << 2) + u) ^ pswz)) = pb;
    }
    __syncthreads();  // (1) P visible

    // ---- PV: 4 kb-groups x [4 P-frag reads + 16 mfma] ----
#pragma unroll
    for (int kb = 0; kb < 4; ++kb) {
      bf16x8 pbr[4];
#pragma unroll
      for (int pg = 0; pg < 4; ++pg) {
        const int rr = (pg << 4) + l16;
        pbr[pg] = *(const bf16x8*)(sP + rr * 256 + 16 * (((kb << 2) + u) ^ (rr & 7)));
      }
#pragma unroll
      for (int ct = 0; ct < 4; ++ct)
#pragma unroll
        for (int pg = 0; pg < 4; ++pg)
          acc[pg][ct] = MFMA16(vr[(kb << 2) + ct], pbr[pg], acc[pg][ct]);
    }
    asm volatile("s_waitcnt vmcnt(0)" ::: "memory");
    __syncthreads();  // (2) K_{t+1} landed; sP/sK reads done
    cur ^= 1;
  }

  // ---- epilogue: share l, per-lane normalize, direct stores ----
  if (lane < 16) sL[(w << 4) + lane] = l_;
  __syncthreads();
#pragma unroll
  for (int pg = 0; pg < 4; ++pg) {
    const float inv = 1.f / sL[(pg << 4) + l16];
    float* ob = out + ((size_t)b << 18) + p0 + (pg << 4) + l16;
#pragma unroll
    for (int ct = 0; ct < 4; ++ct)
#pragma unroll
      for (int r = 0; r < 4; ++r) {
        int c = (w << 6) + (ct << 4) + (u << 2) + r;
        ob[(size_t)c << 10] = acc[pg][ct][r] * inv;
      }
  }
}

// ---------------------------------------------------------------------------
extern "C" void kernel_launch(void* const* d_in, const int* in_sizes, int n_in,
                              void* d_out, int out_size, void* d_ws, size_t ws_size,
                              hipStream_t stream) {
  const float* qf = (const float*)d_in[0];
  const float* kf = (const float*)d_in[1];
  const float* Wq = (const float*)d_in[2];
  const float* bq = (const float*)d_in[3];
  const float* Wk = (const float*)d_in[4];
  const float* bk = (const float*)d_in[5];
  // d_in[6] = vis_CA (unused)
  const int* flag = (const int*)d_in[7];  // same_WqWk
  float* out = (float*)d_out;

  char* ws = (char*)d_ws;
  bf16* Qp = (bf16*)ws;                          // 4 MiB: [32][1024][64] bf16
  bf16* Wbh = (bf16*)(ws + (4u << 20));          // 64 KiB
  bf16* Wbl = (bf16*)(ws + (4u << 20) + 65536);  // 64 KiB
  bf16* KV = (bf16*)(ws + (5u << 20));           // 20 MiB: [32][8] x 81920B chunks

  wprep_kernel<<<32, 256, 0, stream>>>(Wq, Wk, flag, Wbh, Wbl);
  prep_kernel<<<6144, 256, 0, stream>>>(qf, kf, Wbh, Wbl, bq, bk, flag, Qp, KV);
  attn_kernel<<<512, 256, 0, stream>>>(KV, Qp, out);
}

// Round 23
// 64.647 us; speedup vs baseline: 1.2411x; 1.2411x over previous
//
#include <hip/hip_runtime.h>

typedef __bf16 bf16;
typedef __attribute__((ext_vector_type(4))) __bf16 bf16x4;
typedef __attribute__((ext_vector_type(8))) __bf16 bf16x8;
typedef __attribute__((ext_vector_type(4))) float f32x4;
typedef unsigned int u32;

#define MFMA16(a, b, c) __builtin_amdgcn_mfma_f32_16x16x32_bf16((a), (b), (c), 0, 0, 0)
#define LOG2E 1.4426950408889634f
#define AS1 __attribute__((address_space(1)))
#define AS3 __attribute__((address_space(3)))
#define GLL16(g, l) __builtin_amdgcn_global_load_lds((const AS1 u32*)(g), (AS3 u32*)(l), 16, 0, 0)

// KV chunk, per (b, kt=0..7): 81920 bytes =
//  [0,16384):     K tile [128 q][64 o] bf16, identity rows, 16B-blk swz ^(q&7)
//  [16384,81920): V packed for DIRECT wave-fragment loads: octet (c, mm)
//     (mm = kv>>3 within chunk) at byte 16384 + (c>>6)<<14 + (mm>>2)<<12 +
//     ((c>>4)&3)<<10 + (mm&3)<<8 + (c&15)<<4.  attn wave w: load k=4kb+ct at
//     (w<<14)+(k<<10)+(lane<<4) == A-frag (c=64w+16ct+l16, octet mm=4kb+u).

// ---------------------------------------------------------------------------
// Kernel 1: W hi/lo split only (tiny, 32 blocks).
// ---------------------------------------------------------------------------
__global__ __launch_bounds__(256) void wprep_kernel(const float* __restrict__ Wq,
                                                    const float* __restrict__ Wk,
                                                    const int* __restrict__ flag,
                                                    bf16* __restrict__ Wbh,
                                                    bf16* __restrict__ Wbl) {
  const int bx = blockIdx.x, t = threadIdx.x;
  int z = bx >> 4;
  const float* src = (z == 0) ? Wq : ((flag[0] != 0) ? Wq : Wk);
  const float sc = (z == 0) ? LOG2E : 1.0f;  // exp2-domain softmax
  int i = ((((bx & 15) << 8) + t) << 2);
  float4 vv = *(const float4*)(src + i);
  vv.x *= sc; vv.y *= sc; vv.z *= sc; vv.w *= sc;
  bf16x4 hi, lo;
  hi[0] = (bf16)vv.x; lo[0] = (bf16)(vv.x - (float)hi[0]);
  hi[1] = (bf16)vv.y; lo[1] = (bf16)(vv.y - (float)hi[1]);
  hi[2] = (bf16)vv.z; lo[2] = (bf16)(vv.z - (float)hi[2]);
  hi[3] = (bf16)vv.w; lo[3] = (bf16)(vv.w - (float)hi[3]);
  *(bf16x4*)(Wbh + (z << 14) + i) = hi;
  *(bf16x4*)(Wbl + (z << 14) + i) = lo;
}

// ---------------------------------------------------------------------------
// Kernel 2: MERGED proj + V-pack (R20 tiling). Proj inner loop is software-
// pipelined: kk fully unrolled with a double-buffered 32-fp32 x tile so the
// next slice's 32 loads are in flight under the current slice's cvt+MFMA.
// blocks [0,512): projection (128-px tiles, R20 layout).
// blocks [512,4608): kf fp32 -> KV V-region bf16 packed.
// ---------------------------------------------------------------------------
__global__ __launch_bounds__(256) void prep_kernel(const float* __restrict__ qf,
                                                   const float* __restrict__ kf,
                                                   const bf16* __restrict__ Wbh,
                                                   const bf16* __restrict__ Wbl,
                                                   const float* __restrict__ bq,
                                                   const float* __restrict__ bk,
                                                   const int* __restrict__ flag,
                                                   bf16* __restrict__ Qp,
                                                   bf16* __restrict__ KV) {
  const int bid = blockIdx.x, t = threadIdx.x;
  if (bid >= 512) {
    // ---- V-pack: (b, c, q8) -> KV V-region, bf16, fragment-packed ----
    int i = ((bid - 512) << 8) + t;
    int q8 = i & 127, c = (i >> 7) & 255, b = i >> 15;
    const float* src = kf + ((size_t)(((b << 8) + c)) << 10) + (q8 << 3);
    float4 f0 = *(const float4*)src;
    float4 f1 = *(const float4*)(src + 4);
    bf16x8 v;
    v[0] = (bf16)f0.x; v[1] = (bf16)f0.y; v[2] = (bf16)f0.z; v[3] = (bf16)f0.w;
    v[4] = (bf16)f1.x; v[5] = (bf16)f1.y; v[6] = (bf16)f1.z; v[7] = (bf16)f1.w;
    int kt = q8 >> 4, mm = q8 & 15;
    char* dst = (char*)KV + (size_t)((b << 3) + kt) * 81920 + 16384 +
                ((c >> 6) << 14) + ((mm >> 2) << 12) + (((c >> 4) & 3) << 10) +
                ((mm & 3) << 8) + ((c & 15) << 4);
    *(bf16x8*)dst = v;
    return;
  }
  // ---- projection (R20 128-px tiles, pipelined x loads) ----
  const int bx = bid;
  const int x = bx & 7, b = (bx >> 3) & 31, z = bx >> 8;
  const float* xg = z ? kf : qf;
  const bf16* Wh = Wbh + z * 16384;
  const bf16* Wl = Wbl + z * 16384;
  const float* bias = z ? (flag[0] ? bq : bk) : bq;

  const int w = t >> 6, lane = t & 63;
  const int g = lane >> 4, l16 = lane & 15;
  const int wo = w >> 1, wp = w & 1;
  const int o0 = wo << 5;
  const int pbase = (x << 7) + (wp << 6);

  f32x4 acc[2][4];
#pragma unroll
  for (int ot = 0; ot < 2; ++ot) {
    float4 bv = *(const float4*)(bias + o0 + (ot << 4) + (g << 2));
    if (z == 0) { bv.x *= LOG2E; bv.y *= LOG2E; bv.z *= LOG2E; bv.w *= LOG2E; }
#pragma unroll
    for (int pt = 0; pt < 4; ++pt) acc[ot][pt] = (f32x4){bv.x, bv.y, bv.z, bv.w};
  }

  const float* xb = xg + ((((b << 8) + (g << 3)) << 10) + pbase + l16);
  const bf16* whb = Wh + ((o0 + l16) << 8) + (g << 3);
  const bf16* wlb = Wl + ((o0 + l16) << 8) + (g << 3);

  float xbuf[2][4][8];
  // preload kk=0 slice (32 loads in flight)
#pragma unroll
  for (int pt = 0; pt < 4; ++pt)
#pragma unroll
    for (int j = 0; j < 8; ++j) xbuf[0][pt][j] = xb[(j << 10) + (pt << 4)];

#pragma unroll
  for (int kk = 0; kk < 8; ++kk) {
    const int cur = kk & 1;
    // issue next slice's 32 loads first (hide under this slice's compute)
    if (kk < 7) {
      const float* xn = xb + ((kk + 1) << 15);
#pragma unroll
      for (int pt = 0; pt < 4; ++pt)
#pragma unroll
        for (int j = 0; j < 8; ++j) xbuf[cur ^ 1][pt][j] = xn[(j << 10) + (pt << 4)];
    }
    bf16x8 ah[2], al[2];
#pragma unroll
    for (int ot = 0; ot < 2; ++ot) {
      ah[ot] = *(const bf16x8*)(whb + (ot << 12) + (kk << 5));
      al[ot] = *(const bf16x8*)(wlb + (ot << 12) + (kk << 5));
    }
#pragma unroll
    for (int pt = 0; pt < 4; ++pt) {
      bf16x8 xf;
#pragma unroll
      for (int j = 0; j < 8; ++j) xf[j] = (bf16)xbuf[cur][pt][j];
#pragma unroll
      for (int ot = 0; ot < 2; ++ot) {
        acc[ot][pt] = MFMA16(ah[ot], xf, acc[ot][pt]);
        acc[ot][pt] = MFMA16(al[ot], xf, acc[ot][pt]);
      }
    }
  }

#pragma unroll
  for (int ot = 0; ot < 2; ++ot)
#pragma unroll
    for (int pt = 0; pt < 4; ++pt) {
      bf16x4 q4;
#pragma unroll
      for (int r = 0; r < 4; ++r) q4[r] = (bf16)acc[ot][pt][r];
      int p = pbase + (pt << 4) + l16;
      if (z == 0) {
        *(bf16x4*)(Qp + ((((b << 10) + p)) << 6) + o0 + (ot << 4) + (g << 2)) = q4;
      } else {
        int kt = p >> 7, q = p & 127;
        int blk = (o0 >> 3) + (ot << 1) + (g >> 1);
        char* dst = (char*)KV + (size_t)((b << 3) + kt) * 81920 + q * 128 +
                    16 * (blk ^ (q & 7)) + ((g & 1) << 3);
        *(bf16x4*)dst = q4;
      }
    }
}

// ---------------------------------------------------------------------------
// Kernel 3: fused flash attention (R12 verbatim). grid 512 (XCD-swz) x 256.
// KVBLK=128, 8 iters, no-max exp2 softmax, V global->VGPR packed frags,
// P via sP (in-lane octets), K gll dbuf, 2 barriers/iter.
// ---------------------------------------------------------------------------
__global__ __launch_bounds__(256, 2) void attn_kernel(const bf16* __restrict__ KV,
                                                      const bf16* __restrict__ Qp,
                                                      float* __restrict__ out) {
  const int bid = blockIdx.x;
  const int wkid = ((bid & 7) << 6) + (bid >> 3);  // bijective: 512 % 8 == 0
  const int b = wkid >> 4, ptile = wkid & 15;
  const int p0 = ptile << 6;
  const int t = threadIdx.x;
  const int w = t >> 6, lane = t & 63;
  const int u = lane >> 4, l16 = lane & 15;

  __shared__ __align__(16) unsigned char sK[2][16384];  // K dbuf (gll target)
  __shared__ __align__(16) unsigned char sP[16384];     // [64 px][128 kv], swz
  __shared__ float sL[64];

  // Q B-fragments for this wave's 16 px (col=px, k=o)
  const bf16* qb = Qp + (((size_t)((b << 10) + p0 + (w << 4) + l16)) << 6) + (u << 3);
  const bf16x8 qa0 = *(const bf16x8*)qb;
  const bf16x8 qa1 = *(const bf16x8*)(qb + 32);

  const char* chunk0 = (const char*)KV + (size_t)b * (8 * 81920);
  const int Rb = ((l16 >> 2) << 3) + ((l16 & 3) << 1);  // K row perm base

  f32x4 acc[4][4];  // [pg][ct]: c = 64w + 16ct + 4u + r ; px = 16pg + l16
#pragma unroll
  for (int i = 0; i < 4; ++i)
#pragma unroll
    for (int j = 0; j < 4; ++j) acc[i][j] = (f32x4){0.f, 0.f, 0.f, 0.f};
  float l_ = 0.f;

  const int prow = (w << 4) + l16, pswz = prow & 7;

  // ---- prologue: stage K_0 (4 gll/wave) ----
  {
    const char* g = chunk0 + (w << 12) + (lane << 4);
    unsigned char* l = sK[0] + (w << 12);
#pragma unroll
    for (int op = 0; op < 4; ++op) GLL16(g + op * 1024, l + op * 1024);
  }
  asm volatile("s_waitcnt vmcnt(0)" ::: "memory");
  __syncthreads();

  int cur = 0;
  for (int kt = 0; kt < 8; ++kt) {
    // ---- V_t -> regs: 16 coalesced 1KB loads (packed A-fragments) ----
    bf16x8 vr[16];  // vr[4kb+ct] = V A-frag (c=64w+16ct+l16, octet 4kb+u)
    const char* vsrc = chunk0 + kt * 81920 + 16384 + (w << 14) + (lane << 4);
#pragma unroll
    for (int k = 0; k < 16; ++k) vr[k] = *(const bf16x8*)(vsrc + (k << 10));
    // ---- K_{t+1} gll into other buffer ----
    if (kt < 7) {
      const char* g = chunk0 + (kt + 1) * 81920 + (w << 12) + (lane << 4);
      unsigned char* l = sK[cur ^ 1] + (w << 12);
#pragma unroll
      for (int op = 0; op < 4; ++op) GLL16(g + op * 1024, l + op * 1024);
    }
    const unsigned char* sKc = sK[cur];

    // ---- S^T = K·Q^T (16 mfma, permuted K rows from swizzled LDS) ----
    f32x4 s[8];
#pragma unroll
    for (int qt = 0; qt < 8; ++qt) {
      const int R = Rb + (qt & 1) + ((qt >> 1) << 5);
      const int rb = R * 128;
      bf16x8 k0 = *(const bf16x8*)(sKc + rb + 16 * (u ^ (R & 7)));
      bf16x8 k1 = *(const bf16x8*)(sKc + rb + 16 * ((u + 4) ^ (R & 7)));
      f32x4 z = (f32x4){0.f, 0.f, 0.f, 0.f};
      z = MFMA16(k0, qa0, z);
      s[qt] = MFMA16(k1, qa1, z);
    }
    // ---- NO-MAX softmax: P = exp2(S); l += sum ----
#pragma unroll
    for (int qt = 0; qt < 8; ++qt)
#pragma unroll
      for (int r = 0; r < 4; ++r) s[qt][r] = exp2f(s[qt][r]);
    float rs = 0.f;
#pragma unroll
    for (int qt = 0; qt < 8; ++qt)
      rs += (s[qt][0] + s[qt][1]) + (s[qt][2] + s[qt][3]);
    rs += __shfl_xor(rs, 16);
    rs += __shfl_xor(rs, 32);
    l_ += rs;
    // ---- P -> bf16 octets (in-lane), publish 4 b128 ----
#pragma unroll
    for (int a = 0; a < 4; ++a) {
      bf16x8 pb;
#pragma unroll
      for (int r = 0; r < 4; ++r) {
        pb[2 * r] = (bf16)s[2 * a][r];
        pb[2 * r + 1] = (bf16)s[2 * a + 1][r];
      }
      *(bf16x8*)(sP + prow * 256 + 16 * (((a << 2) + u) ^ pswz)) = pb;
    }
    __syncthreads();  // (1) P visible

    // ---- PV: 4 kb-groups x [4 P-frag reads + 16 mfma] ----
#pragma unroll
    for (int kb = 0; kb < 4; ++kb) {
      bf16x8 pbr[4];
#pragma unroll
      for (int pg = 0; pg < 4; ++pg) {
        const int rr = (pg << 4) + l16;
        pbr[pg] = *(const bf16x8*)(sP + rr * 256 + 16 * (((kb << 2) + u) ^ (rr & 7)));
      }
#pragma unroll
      for (int ct = 0; ct < 4; ++ct)
#pragma unroll
        for (int pg = 0; pg < 4; ++pg)
          acc[pg][ct] = MFMA16(vr[(kb << 2) + ct], pbr[pg], acc[pg][ct]);
    }
    asm volatile("s_waitcnt vmcnt(0)" ::: "memory");
    __syncthreads();  // (2) K_{t+1} landed; sP/sK reads done
    cur ^= 1;
  }

  // ---- epilogue: share l, per-lane normalize, direct stores ----
  if (lane < 16) sL[(w << 4) + lane] = l_;
  __syncthreads();
#pragma unroll
  for (int pg = 0; pg < 4; ++pg) {
    const float inv = 1.f / sL[(pg << 4) + l16];
    float* ob = out + ((size_t)b << 18) + p0 + (pg << 4) + l16;
#pragma unroll
    for (int ct = 0; ct < 4; ++ct)
#pragma unroll
      for (int r = 0; r < 4; ++r) {
        int c = (w << 6) + (ct << 4) + (u << 2) + r;
        ob[(size_t)c << 10] = acc[pg][ct][r] * inv;
      }
  }
}

// ---------------------------------------------------------------------------
extern "C" void kernel_launch(void* const* d_in, const int* in_sizes, int n_in,
                              void* d_out, int out_size, void* d_ws, size_t ws_size,
                              hipStream_t stream) {
  const float* qf = (const float*)d_in[0];
  const float* kf = (const float*)d_in[1];
  const float* Wq = (const float*)d_in[2];
  const float* bq = (const float*)d_in[3];
  const float* Wk = (const float*)d_in[4];
  const float* bk = (const float*)d_in[5];
  // d_in[6] = vis_CA (unused)
  const int* flag = (const int*)d_in[7];  // same_WqWk
  float* out = (float*)d_out;

  char* ws = (char*)d_ws;
  bf16* Qp = (bf16*)ws;                          // 4 MiB: [32][1024][64] bf16
  bf16* Wbh = (bf16*)(ws + (4u << 20));          // 64 KiB
  bf16* Wbl = (bf16*)(ws + (4u << 20) + 65536);  // 64 KiB
  bf16* KV = (bf16*)(ws + (5u << 20));           // 20 MiB: [32][8] x 81920B chunks

  wprep_kernel<<<32, 256, 0, stream>>>(Wq, Wk, flag, Wbh, Wbl);
  prep_kernel<<<4608, 256, 0, stream>>>(qf, kf, Wbh, Wbl, bq, bk, flag, Qp, KV);
  attn_kernel<<<512, 256, 0, stream>>>(KV, Qp, out);
}

// Round 24
// 64.113 us; speedup vs baseline: 1.2514x; 1.0083x over previous
//
#include <hip/hip_runtime.h>

typedef __bf16 bf16;
typedef __attribute__((ext_vector_type(4))) __bf16 bf16x4;
typedef __attribute__((ext_vector_type(8))) __bf16 bf16x8;
typedef __attribute__((ext_vector_type(4))) float f32x4;
typedef unsigned int u32;

#define MFMA16(a, b, c) __builtin_amdgcn_mfma_f32_16x16x32_bf16((a), (b), (c), 0, 0, 0)
#define LOG2E 1.4426950408889634f
#define AS1 __attribute__((address_space(1)))
#define AS3 __attribute__((address_space(3)))
#define GLL16(g, l) __builtin_amdgcn_global_load_lds((const AS1 u32*)(g), (AS3 u32*)(l), 16, 0, 0)

// KV chunk, per (b, kt=0..7): 81920 bytes =
//  [0,16384):     K tile [128 q][64 o] bf16, identity rows, 16B-blk swz ^(q&7)
//  [16384,81920): V packed for DIRECT wave-fragment loads: octet (c, mm)
//     at byte 16384 + (c>>6)<<14 + (mm>>2)<<12 + ((c>>4)&3)<<10 + (mm&3)<<8 +
//     (c&15)<<4.  attn wave w: load k=4kb+ct at (w<<14)+(k<<10)+(lane<<4)
//     == A-frag (c=64w+16ct+l16, octet mm=4kb+u).

// ---------------------------------------------------------------------------
// Kernel 1: W hi/lo split only (tiny, 32 blocks).
// ---------------------------------------------------------------------------
__global__ __launch_bounds__(256) void wprep_kernel(const float* __restrict__ Wq,
                                                    const float* __restrict__ Wk,
                                                    const int* __restrict__ flag,
                                                    bf16* __restrict__ Wbh,
                                                    bf16* __restrict__ Wbl) {
  const int bx = blockIdx.x, t = threadIdx.x;
  int z = bx >> 4;
  const float* src = (z == 0) ? Wq : ((flag[0] != 0) ? Wq : Wk);
  const float sc = (z == 0) ? LOG2E : 1.0f;  // exp2-domain softmax
  int i = ((((bx & 15) << 8) + t) << 2);
  float4 vv = *(const float4*)(src + i);
  vv.x *= sc; vv.y *= sc; vv.z *= sc; vv.w *= sc;
  bf16x4 hi, lo;
  hi[0] = (bf16)vv.x; lo[0] = (bf16)(vv.x - (float)hi[0]);
  hi[1] = (bf16)vv.y; lo[1] = (bf16)(vv.y - (float)hi[1]);
  hi[2] = (bf16)vv.z; lo[2] = (bf16)(vv.z - (float)hi[2]);
  hi[3] = (bf16)vv.w; lo[3] = (bf16)(vv.w - (float)hi[3]);
  *(bf16x4*)(Wbh + (z << 14) + i) = hi;
  *(bf16x4*)(Wbl + (z << 14) + i) = lo;
}

// ---------------------------------------------------------------------------
// Kernel 2: unified prep — 512 blocks. Block (x, b, z): stages its x-tile
// [32c x 128px] fp32 into double-buffered LDS (rows padded to 130 floats);
// one barrier/iter. z=1 additionally converts the staged tile to bf16 V
// octets -> packed KV V-region (same data; kf read ONCE total). MFMA B-frags
// come from LDS (bit-identical cvt). z=0 -> Qp; z=1 -> KV K-part.
// ---------------------------------------------------------------------------
__global__ __launch_bounds__(256) void prep_kernel(const float* __restrict__ qf,
                                                   const float* __restrict__ kf,
                                                   const bf16* __restrict__ Wbh,
                                                   const bf16* __restrict__ Wbl,
                                                   const float* __restrict__ bq,
                                                   const float* __restrict__ bk,
                                                   const int* __restrict__ flag,
                                                   bf16* __restrict__ Qp,
                                                   bf16* __restrict__ KV) {
  const int bid = blockIdx.x, t = threadIdx.x;
  const int x = bid & 7, b = (bid >> 3) & 31, z = bid >> 8;
  const float* xg = z ? kf : qf;
  const bf16* Wh = Wbh + z * 16384;
  const bf16* Wl = Wbl + z * 16384;
  const float* bias = z ? (flag[0] ? bq : bk) : bq;

  const int w = t >> 6, lane = t & 63;
  const int g = lane >> 4, l16 = lane & 15;
  const int wo = w >> 1, wp = w & 1;
  const int o0 = wo << 5;
  const int pbase = (x << 7) + (wp << 6);
  const int qloc = (wp << 6) + l16;  // + pt*16 at use

  __shared__ float sX[2][4160];  // 2 x [32 c][130 floats] (pad: 2-way reads)

  // staging decomposition: it 0..1 -> c_local = (it<<4)+(t>>4), oct = t&15
  const int cl0 = t >> 4, oct = t & 15;
  const float* srcb = xg + (((size_t)((b << 8) + cl0)) << 10) + (x << 7) + (oct << 3);
  char* vdst0 = (char*)KV + (size_t)((b << 3) + x) * 81920 + 16384;  // z==1

  f32x4 acc[2][4];
#pragma unroll
  for (int ot = 0; ot < 2; ++ot) {
    float4 bv = *(const float4*)(bias + o0 + (ot << 4) + (g << 2));
    if (z == 0) { bv.x *= LOG2E; bv.y *= LOG2E; bv.z *= LOG2E; bv.w *= LOG2E; }
#pragma unroll
    for (int pt = 0; pt < 4; ++pt) acc[ot][pt] = (f32x4){bv.x, bv.y, bv.z, bv.w};
  }

  const bf16* whb = Wh + ((o0 + l16) << 8) + (g << 3);
  const bf16* wlb = Wl + ((o0 + l16) << 8) + (g << 3);

  // ---- prologue: stage slice kk=0 into buf 0 (+ V octets if z==1) ----
#pragma unroll
  for (int it = 0; it < 2; ++it) {
    const int cl = (it << 4) + cl0;
    const float* s = srcb + ((size_t)it << 14);
    float4 f0 = *(const float4*)s;
    float4 f1 = *(const float4*)(s + 4);
    float* d = &sX[0][cl * 130 + (oct << 3)];
    *(float2*)(d + 0) = make_float2(f0.x, f0.y);
    *(float2*)(d + 2) = make_float2(f0.z, f0.w);
    *(float2*)(d + 4) = make_float2(f1.x, f1.y);
    *(float2*)(d + 6) = make_float2(f1.z, f1.w);
    if (z) {
      int cg = cl;
      bf16x8 v;
      v[0] = (bf16)f0.x; v[1] = (bf16)f0.y; v[2] = (bf16)f0.z; v[3] = (bf16)f0.w;
      v[4] = (bf16)f1.x; v[5] = (bf16)f1.y; v[6] = (bf16)f1.z; v[7] = (bf16)f1.w;
      char* dst = vdst0 + ((cg >> 6) << 14) + ((oct >> 2) << 12) +
                  (((cg >> 4) & 3) << 10) + ((oct & 3) << 8) + ((cg & 15) << 4);
      *(bf16x8*)dst = v;
    }
  }
  __syncthreads();

#pragma unroll
  for (int kk = 0; kk < 8; ++kk) {
    // ---- stage slice kk+1 into other buffer (latency hides under compute) ----
    if (kk < 7) {
      const int bi = (kk + 1) & 1;
#pragma unroll
      for (int it = 0; it < 2; ++it) {
        const int cl = (it << 4) + cl0;
        const float* s = srcb + ((size_t)it << 14) + ((size_t)(kk + 1) << 15);
        float4 f0 = *(const float4*)s;
        float4 f1 = *(const float4*)(s + 4);
        float* d = &sX[bi][cl * 130 + (oct << 3)];
        *(float2*)(d + 0) = make_float2(f0.x, f0.y);
        *(float2*)(d + 2) = make_float2(f0.z, f0.w);
        *(float2*)(d + 4) = make_float2(f1.x, f1.y);
        *(float2*)(d + 6) = make_float2(f1.z, f1.w);
        if (z) {
          int cg = ((kk + 1) << 5) + cl;
          bf16x8 v;
          v[0] = (bf16)f0.x; v[1] = (bf16)f0.y; v[2] = (bf16)f0.z; v[3] = (bf16)f0.w;
          v[4] = (bf16)f1.x; v[5] = (bf16)f1.y; v[6] = (bf16)f1.z; v[7] = (bf16)f1.w;
          char* dst = vdst0 + ((cg >> 6) << 14) + ((oct >> 2) << 12) +
                      (((cg >> 4) & 3) << 10) + ((oct & 3) << 8) + ((cg & 15) << 4);
          *(bf16x8*)dst = v;
        }
      }
    }
    // ---- compute slice kk from buf kk&1 ----
    const float* sb = sX[kk & 1];
    bf16x8 ah[2], al[2];
#pragma unroll
    for (int ot = 0; ot < 2; ++ot) {
      ah[ot] = *(const bf16x8*)(whb + (ot << 12) + (kk << 5));
      al[ot] = *(const bf16x8*)(wlb + (ot << 12) + (kk << 5));
    }
#pragma unroll
    for (int pt = 0; pt < 4; ++pt) {
      bf16x8 xf;
#pragma unroll
      for (int j = 0; j < 8; ++j)
        xf[j] = (bf16)sb[(((g << 3) + j) * 130) + qloc + (pt << 4)];
#pragma unroll
      for (int ot = 0; ot < 2; ++ot) {
        acc[ot][pt] = MFMA16(ah[ot], xf, acc[ot][pt]);
        acc[ot][pt] = MFMA16(al[ot], xf, acc[ot][pt]);
      }
    }
    __syncthreads();  // staging(kk+1) visible; compute(kk) done before reuse
  }

#pragma unroll
  for (int ot = 0; ot < 2; ++ot)
#pragma unroll
    for (int pt = 0; pt < 4; ++pt) {
      bf16x4 q4;
#pragma unroll
      for (int r = 0; r < 4; ++r) q4[r] = (bf16)acc[ot][pt][r];
      int p = pbase + (pt << 4) + l16;
      if (z == 0) {
        *(bf16x4*)(Qp + ((((b << 10) + p)) << 6) + o0 + (ot << 4) + (g << 2)) = q4;
      } else {
        int kt = p >> 7, q = p & 127;
        int blk = (o0 >> 3) + (ot << 1) + (g >> 1);
        char* dst = (char*)KV + (size_t)((b << 3) + kt) * 81920 + q * 128 +
                    16 * (blk ^ (q & 7)) + ((g & 1) << 3);
        *(bf16x4*)dst = q4;
      }
    }
}

// ---------------------------------------------------------------------------
// Kernel 3: fused flash attention (R12 verbatim). grid 512 (XCD-swz) x 256.
// KVBLK=128, 8 iters, no-max exp2 softmax, V global->VGPR packed frags,
// P via sP (in-lane octets), K gll dbuf, 2 barriers/iter.
// ---------------------------------------------------------------------------
__global__ __launch_bounds__(256, 2) void attn_kernel(const bf16* __restrict__ KV,
                                                      const bf16* __restrict__ Qp,
                                                      float* __restrict__ out) {
  const int bid = blockIdx.x;
  const int wkid = ((bid & 7) << 6) + (bid >> 3);  // bijective: 512 % 8 == 0
  const int b = wkid >> 4, ptile = wkid & 15;
  const int p0 = ptile << 6;
  const int t = threadIdx.x;
  const int w = t >> 6, lane = t & 63;
  const int u = lane >> 4, l16 = lane & 15;

  __shared__ __align__(16) unsigned char sK[2][16384];  // K dbuf (gll target)
  __shared__ __align__(16) unsigned char sP[16384];     // [64 px][128 kv], swz
  __shared__ float sL[64];

  // Q B-fragments for this wave's 16 px (col=px, k=o)
  const bf16* qb = Qp + (((size_t)((b << 10) + p0 + (w << 4) + l16)) << 6) + (u << 3);
  const bf16x8 qa0 = *(const bf16x8*)qb;
  const bf16x8 qa1 = *(const bf16x8*)(qb + 32);

  const char* chunk0 = (const char*)KV + (size_t)b * (8 * 81920);
  const int Rb = ((l16 >> 2) << 3) + ((l16 & 3) << 1);  // K row perm base

  f32x4 acc[4][4];  // [pg][ct]: c = 64w + 16ct + 4u + r ; px = 16pg + l16
#pragma unroll
  for (int i = 0; i < 4; ++i)
#pragma unroll
    for (int j = 0; j < 4; ++j) acc[i][j] = (f32x4){0.f, 0.f, 0.f, 0.f};
  float l_ = 0.f;

  const int prow = (w << 4) + l16, pswz = prow & 7;

  // ---- prologue: stage K_0 (4 gll/wave) ----
  {
    const char* g = chunk0 + (w << 12) + (lane << 4);
    unsigned char* l = sK[0] + (w << 12);
#pragma unroll
    for (int op = 0; op < 4; ++op) GLL16(g + op * 1024, l + op * 1024);
  }
  asm volatile("s_waitcnt vmcnt(0)" ::: "memory");
  __syncthreads();

  int cur = 0;
  for (int kt = 0; kt < 8; ++kt) {
    // ---- V_t -> regs: 16 coalesced 1KB loads (packed A-fragments) ----
    bf16x8 vr[16];  // vr[4kb+ct] = V A-frag (c=64w+16ct+l16, octet 4kb+u)
    const char* vsrc = chunk0 + kt * 81920 + 16384 + (w << 14) + (lane << 4);
#pragma unroll
    for (int k = 0; k < 16; ++k) vr[k] = *(const bf16x8*)(vsrc + (k << 10));
    // ---- K_{t+1} gll into other buffer ----
    if (kt < 7) {
      const char* g = chunk0 + (kt + 1) * 81920 + (w << 12) + (lane << 4);
      unsigned char* l = sK[cur ^ 1] + (w << 12);
#pragma unroll
      for (int op = 0; op < 4; ++op) GLL16(g + op * 1024, l + op * 1024);
    }
    const unsigned char* sKc = sK[cur];

    // ---- S^T = K·Q^T (16 mfma, permuted K rows from swizzled LDS) ----
    f32x4 s[8];
#pragma unroll
    for (int qt = 0; qt < 8; ++qt) {
      const int R = Rb + (qt & 1) + ((qt >> 1) << 5);
      const int rb = R * 128;
      bf16x8 k0 = *(const bf16x8*)(sKc + rb + 16 * (u ^ (R & 7)));
      bf16x8 k1 = *(const bf16x8*)(sKc + rb + 16 * ((u + 4) ^ (R & 7)));
      f32x4 z = (f32x4){0.f, 0.f, 0.f, 0.f};
      z = MFMA16(k0, qa0, z);
      s[qt] = MFMA16(k1, qa1, z);
    }
    // ---- NO-MAX softmax: P = exp2(S); l += sum ----
#pragma unroll
    for (int qt = 0; qt < 8; ++qt)
#pragma unroll
      for (int r = 0; r < 4; ++r) s[qt][r] = exp2f(s[qt][r]);
    float rs = 0.f;
#pragma unroll
    for (int qt = 0; qt < 8; ++qt)
      rs += (s[qt][0] + s[qt][1]) + (s[qt][2] + s[qt][3]);
    rs += __shfl_xor(rs, 16);
    rs += __shfl_xor(rs, 32);
    l_ += rs;
    // ---- P -> bf16 octets (in-lane), publish 4 b128 ----
#pragma unroll
    for (int a = 0; a < 4; ++a) {
      bf16x8 pb;
#pragma unroll
      for (int r = 0; r < 4; ++r) {
        pb[2 * r] = (bf16)s[2 * a][r];
        pb[2 * r + 1] = (bf16)s[2 * a + 1][r];
      }
      *(bf16x8*)(sP + prow * 256 + 16 * (((a << 2) + u) ^ pswz)) = pb;
    }
    __syncthreads();  // (1) P visible

    // ---- PV: 4 kb-groups x [4 P-frag reads + 16 mfma] ----
#pragma unroll
    for (int kb = 0; kb < 4; ++kb) {
      bf16x8 pbr[4];
#pragma unroll
      for (int pg = 0; pg < 4; ++pg) {
        const int rr = (pg << 4) + l16;
        pbr[pg] = *(const bf16x8*)(sP + rr * 256 + 16 * (((kb << 2) + u) ^ (rr & 7)));
      }
#pragma unroll
      for (int ct = 0; ct < 4; ++ct)
#pragma unroll
        for (int pg = 0; pg < 4; ++pg)
          acc[pg][ct] = MFMA16(vr[(kb << 2) + ct], pbr[pg], acc[pg][ct]);
    }
    asm volatile("s_waitcnt vmcnt(0)" ::: "memory");
    __syncthreads();  // (2) K_{t+1} landed; sP/sK reads done
    cur ^= 1;
  }

  // ---- epilogue: share l, per-lane normalize, direct stores ----
  if (lane < 16) sL[(w << 4) + lane] = l_;
  __syncthreads();
#pragma unroll
  for (int pg = 0; pg < 4; ++pg) {
    const float inv = 1.f / sL[(pg << 4) + l16];
    float* ob = out + ((size_t)b << 18) + p0 + (pg << 4) + l16;
#pragma unroll
    for (int ct = 0; ct < 4; ++ct)
#pragma unroll
      for (int r = 0; r < 4; ++r) {
        int c = (w << 6) + (ct << 4) + (u << 2) + r;
        ob[(size_t)c << 10] = acc[pg][ct][r] * inv;
      }
  }
}

// ---------------------------------------------------------------------------
extern "C" void kernel_launch(void* const* d_in, const int* in_sizes, int n_in,
                              void* d_out, int out_size, void* d_ws, size_t ws_size,
                              hipStream_t stream) {
  const float* qf = (const float*)d_in[0];
  const float* kf = (const float*)d_in[1];
  const float* Wq = (const float*)d_in[2];
  const float* bq = (const float*)d_in[3];
  const float* Wk = (const float*)d_in[4];
  const float* bk = (const float*)d_in[5];
  // d_in[6] = vis_CA (unused)
  const int* flag = (const int*)d_in[7];  // same_WqWk
  float* out = (float*)d_out;

  char* ws = (char*)d_ws;
  bf16* Qp = (bf16*)ws;                          // 4 MiB: [32][1024][64] bf16
  bf16* Wbh = (bf16*)(ws + (4u << 20));          // 64 KiB
  bf16* Wbl = (bf16*)(ws + (4u << 20) + 65536);  // 64 KiB
  bf16* KV = (bf16*)(ws + (5u << 20));           // 20 MiB: [32][8] x 81920B chunks

  wprep_kernel<<<32, 256, 0, stream>>>(Wq, Wk, flag, Wbh, Wbl);
  prep_kernel<<<512, 256, 0, stream>>>(qf, kf, Wbh, Wbl, bq, bk, flag, Qp, KV);
  attn_kernel<<<512, 256, 0, stream>>>(KV, Qp, out);
}

// Round 25
// 55.019 us; speedup vs baseline: 1.4583x; 1.1653x over previous
//
#include <hip/hip_runtime.h>

typedef __bf16 bf16;
typedef __attribute__((ext_vector_type(4))) __bf16 bf16x4;
typedef __attribute__((ext_vector_type(8))) __bf16 bf16x8;
typedef __attribute__((ext_vector_type(4))) float f32x4;
typedef unsigned int u32;

#define MFMA16(a, b, c) __builtin_amdgcn_mfma_f32_16x16x32_bf16((a), (b), (c), 0, 0, 0)
#define LOG2E 1.4426950408889634f
#define AS1 __attribute__((address_space(1)))
#define AS3 __attribute__((address_space(3)))
#define GLL16(g, l) __builtin_amdgcn_global_load_lds((const AS1 u32*)(g), (AS3 u32*)(l), 16, 0, 0)

// KV chunk, per (b, kt=0..7): 81920 bytes =
//  [0,16384):     K tile [128 q][64 o] bf16, identity rows, 16B-blk swz ^(q&7)
//  [16384,81920): V packed for DIRECT wave-fragment loads: octet (c, mm)
//     at byte 16384 + (c>>6)<<14 + (mm>>2)<<12 + ((c>>4)&3)<<10 + (mm&3)<<8 +
//     (c&15)<<4.  attn wave w: load k=4kb+ct at (w<<14)+(k<<10)+(lane<<4)
//     == A-frag (c=64w+16ct+l16, octet mm=4kb+u).

// ---------------------------------------------------------------------------
// Kernel 1: unified prep — 512 blocks, W hi/lo split computed INLINE from
// fp32 W (bit-identical to the old wprep; W is L2-resident so traffic equal).
// Block (x, b, z): stages its x-tile [32c x 128px] fp32 into double-buffered
// LDS; z=1 additionally emits the staged tile as packed bf16 V octets (kf
// read ONCE). z=0 -> Qp (log2e-scaled); z=1 -> KV K-part.
// ---------------------------------------------------------------------------
__global__ __launch_bounds__(256) void prep_kernel(const float* __restrict__ qf,
                                                   const float* __restrict__ kf,
                                                   const float* __restrict__ Wq,
                                                   const float* __restrict__ Wk,
                                                   const float* __restrict__ bq,
                                                   const float* __restrict__ bk,
                                                   const int* __restrict__ flag,
                                                   bf16* __restrict__ Qp,
                                                   bf16* __restrict__ KV) {
  const int bid = blockIdx.x, t = threadIdx.x;
  const int x = bid & 7, b = (bid >> 3) & 31, z = bid >> 8;
  const float* xg = z ? kf : qf;
  const float* Wsrc = z ? (flag[0] ? Wq : Wk) : Wq;
  const float wsc = z ? 1.0f : LOG2E;
  const float* bias = z ? (flag[0] ? bq : bk) : bq;

  const int w = t >> 6, lane = t & 63;
  const int g = lane >> 4, l16 = lane & 15;
  const int wo = w >> 1, wp = w & 1;
  const int o0 = wo << 5;
  const int pbase = (x << 7) + (wp << 6);
  const int qloc = (wp << 6) + l16;  // + pt*16 at use

  __shared__ float sX[2][4160];  // 2 x [32 c][130 floats] (pad: 2-way reads)

  // staging decomposition: it 0..1 -> c_local = (it<<4)+(t>>4), oct = t&15
  const int cl0 = t >> 4, oct = t & 15;
  const float* srcb = xg + (((size_t)((b << 8) + cl0)) << 10) + (x << 7) + (oct << 3);
  char* vdst0 = (char*)KV + (size_t)((b << 3) + x) * 81920 + 16384;  // z==1

  f32x4 acc[2][4];
#pragma unroll
  for (int ot = 0; ot < 2; ++ot) {
    float4 bv = *(const float4*)(bias + o0 + (ot << 4) + (g << 2));
    if (z == 0) { bv.x *= LOG2E; bv.y *= LOG2E; bv.z *= LOG2E; bv.w *= LOG2E; }
#pragma unroll
    for (int pt = 0; pt < 4; ++pt) acc[ot][pt] = (f32x4){bv.x, bv.y, bv.z, bv.w};
  }

  // W fp32 base for this lane's two A-frag rows (o0+l16, o0+16+l16)
  const float* wrow = Wsrc + ((o0 + l16) << 8) + (g << 3);

  // ---- prologue: stage slice kk=0 into buf 0 (+ V octets if z==1) ----
#pragma unroll
  for (int it = 0; it < 2; ++it) {
    const int cl = (it << 4) + cl0;
    const float* s = srcb + ((size_t)it << 14);
    float4 f0 = *(const float4*)s;
    float4 f1 = *(const float4*)(s + 4);
    float* d = &sX[0][cl * 130 + (oct << 3)];
    *(float2*)(d + 0) = make_float2(f0.x, f0.y);
    *(float2*)(d + 2) = make_float2(f0.z, f0.w);
    *(float2*)(d + 4) = make_float2(f1.x, f1.y);
    *(float2*)(d + 6) = make_float2(f1.z, f1.w);
    if (z) {
      int cg = cl;
      bf16x8 v;
      v[0] = (bf16)f0.x; v[1] = (bf16)f0.y; v[2] = (bf16)f0.z; v[3] = (bf16)f0.w;
      v[4] = (bf16)f1.x; v[5] = (bf16)f1.y; v[6] = (bf16)f1.z; v[7] = (bf16)f1.w;
      char* dst = vdst0 + ((cg >> 6) << 14) + ((oct >> 2) << 12) +
                  (((cg >> 4) & 3) << 10) + ((oct & 3) << 8) + ((cg & 15) << 4);
      *(bf16x8*)dst = v;
    }
  }
  __syncthreads();

#pragma unroll
  for (int kk = 0; kk < 8; ++kk) {
    // ---- stage slice kk+1 into other buffer (latency hides under compute) ----
    if (kk < 7) {
      const int bi = (kk + 1) & 1;
#pragma unroll
      for (int it = 0; it < 2; ++it) {
        const int cl = (it << 4) + cl0;
        const float* s = srcb + ((size_t)it << 14) + ((size_t)(kk + 1) << 15);
        float4 f0 = *(const float4*)s;
        float4 f1 = *(const float4*)(s + 4);
        float* d = &sX[bi][cl * 130 + (oct << 3)];
        *(float2*)(d + 0) = make_float2(f0.x, f0.y);
        *(float2*)(d + 2) = make_float2(f0.z, f0.w);
        *(float2*)(d + 4) = make_float2(f1.x, f1.y);
        *(float2*)(d + 6) = make_float2(f1.z, f1.w);
        if (z) {
          int cg = ((kk + 1) << 5) + cl;
          bf16x8 v;
          v[0] = (bf16)f0.x; v[1] = (bf16)f0.y; v[2] = (bf16)f0.z; v[3] = (bf16)f0.w;
          v[4] = (bf16)f1.x; v[5] = (bf16)f1.y; v[6] = (bf16)f1.z; v[7] = (bf16)f1.w;
          char* dst = vdst0 + ((cg >> 6) << 14) + ((oct >> 2) << 12) +
                      (((cg >> 4) & 3) << 10) + ((oct & 3) << 8) + ((cg & 15) << 4);
          *(bf16x8*)dst = v;
        }
      }
    }
    // ---- W A-frags inline from fp32 (hi/lo split, wprep-identical) ----
    bf16x8 ah[2], al[2];
#pragma unroll
    for (int ot = 0; ot < 2; ++ot) {
      const float* wr = wrow + (ot << 12) + (kk << 5);
      float4 w0 = *(const float4*)wr;
      float4 w1 = *(const float4*)(wr + 4);
      float wv[8] = {w0.x, w0.y, w0.z, w0.w, w1.x, w1.y, w1.z, w1.w};
#pragma unroll
      for (int j = 0; j < 8; ++j) {
        float sw = wv[j] * wsc;
        bf16 h = (bf16)sw;
        ah[ot][j] = h;
        al[ot][j] = (bf16)(sw - (float)h);
      }
    }
    // ---- compute slice kk from buf kk&1 ----
    const float* sb = sX[kk & 1];
#pragma unroll
    for (int pt = 0; pt < 4; ++pt) {
      bf16x8 xf;
#pragma unroll
      for (int j = 0; j < 8; ++j)
        xf[j] = (bf16)sb[(((g << 3) + j) * 130) + qloc + (pt << 4)];
#pragma unroll
      for (int ot = 0; ot < 2; ++ot) {
        acc[ot][pt] = MFMA16(ah[ot], xf, acc[ot][pt]);
        acc[ot][pt] = MFMA16(al[ot], xf, acc[ot][pt]);
      }
    }
    __syncthreads();  // staging(kk+1) visible; compute(kk) done before reuse
  }

#pragma unroll
  for (int ot = 0; ot < 2; ++ot)
#pragma unroll
    for (int pt = 0; pt < 4; ++pt) {
      bf16x4 q4;
#pragma unroll
      for (int r = 0; r < 4; ++r) q4[r] = (bf16)acc[ot][pt][r];
      int p = pbase + (pt << 4) + l16;
      if (z == 0) {
        *(bf16x4*)(Qp + ((((b << 10) + p)) << 6) + o0 + (ot << 4) + (g << 2)) = q4;
      } else {
        int kt = p >> 7, q = p & 127;
        int blk = (o0 >> 3) + (ot << 1) + (g >> 1);
        char* dst = (char*)KV + (size_t)((b << 3) + kt) * 81920 + q * 128 +
                    16 * (blk ^ (q & 7)) + ((g & 1) << 3);
        *(bf16x4*)dst = q4;
      }
    }
}

// ---------------------------------------------------------------------------
// Kernel 2: fused flash attention (R12 verbatim). grid 512 (XCD-swz) x 256.
// KVBLK=128, 8 iters, no-max exp2 softmax, V global->VGPR packed frags,
// P via sP (in-lane octets), K gll dbuf, 2 barriers/iter.
// ---------------------------------------------------------------------------
__global__ __launch_bounds__(256, 2) void attn_kernel(const bf16* __restrict__ KV,
                                                      const bf16* __restrict__ Qp,
                                                      float* __restrict__ out) {
  const int bid = blockIdx.x;
  const int wkid = ((bid & 7) << 6) + (bid >> 3);  // bijective: 512 % 8 == 0
  const int b = wkid >> 4, ptile = wkid & 15;
  const int p0 = ptile << 6;
  const int t = threadIdx.x;
  const int w = t >> 6, lane = t & 63;
  const int u = lane >> 4, l16 = lane & 15;

  __shared__ __align__(16) unsigned char sK[2][16384];  // K dbuf (gll target)
  __shared__ __align__(16) unsigned char sP[16384];     // [64 px][128 kv], swz
  __shared__ float sL[64];

  // Q B-fragments for this wave's 16 px (col=px, k=o)
  const bf16* qb = Qp + (((size_t)((b << 10) + p0 + (w << 4) + l16)) << 6) + (u << 3);
  const bf16x8 qa0 = *(const bf16x8*)qb;
  const bf16x8 qa1 = *(const bf16x8*)(qb + 32);

  const char* chunk0 = (const char*)KV + (size_t)b * (8 * 81920);
  const int Rb = ((l16 >> 2) << 3) + ((l16 & 3) << 1);  // K row perm base

  f32x4 acc[4][4];  // [pg][ct]: c = 64w + 16ct + 4u + r ; px = 16pg + l16
#pragma unroll
  for (int i = 0; i < 4; ++i)
#pragma unroll
    for (int j = 0; j < 4; ++j) acc[i][j] = (f32x4){0.f, 0.f, 0.f, 0.f};
  float l_ = 0.f;

  const int prow = (w << 4) + l16, pswz = prow & 7;

  // ---- prologue: stage K_0 (4 gll/wave) ----
  {
    const char* g = chunk0 + (w << 12) + (lane << 4);
    unsigned char* l = sK[0] + (w << 12);
#pragma unroll
    for (int op = 0; op < 4; ++op) GLL16(g + op * 1024, l + op * 1024);
  }
  asm volatile("s_waitcnt vmcnt(0)" ::: "memory");
  __syncthreads();

  int cur = 0;
  for (int kt = 0; kt < 8; ++kt) {
    // ---- V_t -> regs: 16 coalesced 1KB loads (packed A-fragments) ----
    bf16x8 vr[16];  // vr[4kb+ct] = V A-frag (c=64w+16ct+l16, octet 4kb+u)
    const char* vsrc = chunk0 + kt * 81920 + 16384 + (w << 14) + (lane << 4);
#pragma unroll
    for (int k = 0; k < 16; ++k) vr[k] = *(const bf16x8*)(vsrc + (k << 10));
    // ---- K_{t+1} gll into other buffer ----
    if (kt < 7) {
      const char* g = chunk0 + (kt + 1) * 81920 + (w << 12) + (lane << 4);
      unsigned char* l = sK[cur ^ 1] + (w << 12);
#pragma unroll
      for (int op = 0; op < 4; ++op) GLL16(g + op * 1024, l + op * 1024);
    }
    const unsigned char* sKc = sK[cur];

    // ---- S^T = K·Q^T (16 mfma, permuted K rows from swizzled LDS) ----
    f32x4 s[8];
#pragma unroll
    for (int qt = 0; qt < 8; ++qt) {
      const int R = Rb + (qt & 1) + ((qt >> 1) << 5);
      const int rb = R * 128;
      bf16x8 k0 = *(const bf16x8*)(sKc + rb + 16 * (u ^ (R & 7)));
      bf16x8 k1 = *(const bf16x8*)(sKc + rb + 16 * ((u + 4) ^ (R & 7)));
      f32x4 z = (f32x4){0.f, 0.f, 0.f, 0.f};
      z = MFMA16(k0, qa0, z);
      s[qt] = MFMA16(k1, qa1, z);
    }
    // ---- NO-MAX softmax: P = exp2(S); l += sum ----
#pragma unroll
    for (int qt = 0; qt < 8; ++qt)
#pragma unroll
      for (int r = 0; r < 4; ++r) s[qt][r] = exp2f(s[qt][r]);
    float rs = 0.f;
#pragma unroll
    for (int qt = 0; qt < 8; ++qt)
      rs += (s[qt][0] + s[qt][1]) + (s[qt][2] + s[qt][3]);
    rs += __shfl_xor(rs, 16);
    rs += __shfl_xor(rs, 32);
    l_ += rs;
    // ---- P -> bf16 octets (in-lane), publish 4 b128 ----
#pragma unroll
    for (int a = 0; a < 4; ++a) {
      bf16x8 pb;
#pragma unroll
      for (int r = 0; r < 4; ++r) {
        pb[2 * r] = (bf16)s[2 * a][r];
        pb[2 * r + 1] = (bf16)s[2 * a + 1][r];
      }
      *(bf16x8*)(sP + prow * 256 + 16 * (((a << 2) + u) ^ pswz)) = pb;
    }
    __syncthreads();  // (1) P visible

    // ---- PV: 4 kb-groups x [4 P-frag reads + 16 mfma] ----
#pragma unroll
    for (int kb = 0; kb < 4; ++kb) {
      bf16x8 pbr[4];
#pragma unroll
      for (int pg = 0; pg < 4; ++pg) {
        const int rr = (pg << 4) + l16;
        pbr[pg] = *(const bf16x8*)(sP + rr * 256 + 16 * (((kb << 2) + u) ^ (rr & 7)));
      }
#pragma unroll
      for (int ct = 0; ct < 4; ++ct)
#pragma unroll
        for (int pg = 0; pg < 4; ++pg)
          acc[pg][ct] = MFMA16(vr[(kb << 2) + ct], pbr[pg], acc[pg][ct]);
    }
    asm volatile("s_waitcnt vmcnt(0)" ::: "memory");
    __syncthreads();  // (2) K_{t+1} landed; sP/sK reads done
    cur ^= 1;
  }

  // ---- epilogue: share l, per-lane normalize, direct stores ----
  if (lane < 16) sL[(w << 4) + lane] = l_;
  __syncthreads();
#pragma unroll
  for (int pg = 0; pg < 4; ++pg) {
    const float inv = 1.f / sL[(pg << 4) + l16];
    float* ob = out + ((size_t)b << 18) + p0 + (pg << 4) + l16;
#pragma unroll
    for (int ct = 0; ct < 4; ++ct)
#pragma unroll
      for (int r = 0; r < 4; ++r) {
        int c = (w << 6) + (ct << 4) + (u << 2) + r;
        ob[(size_t)c << 10] = acc[pg][ct][r] * inv;
      }
  }
}

// ---------------------------------------------------------------------------
extern "C" void kernel_launch(void* const* d_in, const int* in_sizes, int n_in,
                              void* d_out, int out_size, void* d_ws, size_t ws_size,
                              hipStream_t stream) {
  const float* qf = (const float*)d_in[0];
  const float* kf = (const float*)d_in[1];
  const float* Wq = (const float*)d_in[2];
  const float* bq = (const float*)d_in[3];
  const float* Wk = (const float*)d_in[4];
  const float* bk = (const float*)d_in[5];
  // d_in[6] = vis_CA (unused)
  const int* flag = (const int*)d_in[7];  // same_WqWk
  float* out = (float*)d_out;

  char* ws = (char*)d_ws;
  bf16* Qp = (bf16*)ws;                          // 4 MiB: [32][1024][64] bf16
  bf16* KV = (bf16*)(ws + (5u << 20));           // 20 MiB: [32][8] x 81920B chunks

  prep_kernel<<<512, 256, 0, stream>>>(qf, kf, Wq, Wk, bq, bk, flag, Qp, KV);
  attn_kernel<<<512, 256, 0, stream>>>(KV, Qp, out);
}